// Round 1
// baseline (455.980 us; speedup 1.0000x reference)
//
#include <hip/hip_runtime.h>

#define NFEAT 42
#define H1 256
#define H2 128
#define H3 64
#define NB 8
#define NA 512
#define NM 100

// -------- Kernel 1: per-atom MLP forward + backward (dE/dx) --------
// one block (256 threads) per atom
__global__ __launch_bounds__(256) void mlp_fwd_bwd(
    const float* __restrict__ image,
    const float* __restrict__ W0, const float* __restrict__ b0,
    const float* __restrict__ W1, const float* __restrict__ b1,
    const float* __restrict__ W2, const float* __restrict__ b2,
    const float* __restrict__ W3, const float* __restrict__ b3,
    float* __restrict__ Ei,   // [B*N]
    float* __restrict__ dE)   // [B*N, NFEAT]
{
    const int atom = blockIdx.x;
    const int t = threadIdx.x;

    __shared__ float sx[NFEAT];
    __shared__ float sh1[H1], sh2[H2], sh3[H3];
    __shared__ float sd3[H3], sd2[H2], sd1[H1];

    if (t < NFEAT) sx[t] = image[atom * NFEAT + t];
    __syncthreads();

    // layer 0: 42 -> 256, sigmoid
    {
        float z = b0[t];
        #pragma unroll
        for (int f = 0; f < NFEAT; ++f) z += sx[f] * W0[f * H1 + t];
        sh1[t] = 1.0f / (1.0f + expf(-z));
    }
    __syncthreads();

    // layer 1: 256 -> 128, sigmoid
    if (t < H2) {
        float z = b1[t];
        #pragma unroll 8
        for (int k = 0; k < H1; ++k) z += sh1[k] * W1[k * H2 + t];
        sh2[t] = 1.0f / (1.0f + expf(-z));
    }
    __syncthreads();

    // layer 2: 128 -> 64, sigmoid
    if (t < H3) {
        float z = b2[t];
        #pragma unroll 8
        for (int k = 0; k < H2; ++k) z += sh2[k] * W2[k * H3 + t];
        sh3[t] = 1.0f / (1.0f + expf(-z));
    }
    __syncthreads();

    // output layer (64 -> 1, linear) + d3 = W3 * h3*(1-h3)
    if (t < H3) {   // single wave (lanes 0..63)
        float h = sh3[t];
        float w = W3[t];
        sd3[t] = w * h * (1.0f - h);
        float v = w * h;
        #pragma unroll
        for (int off = 32; off > 0; off >>= 1) v += __shfl_down(v, off, 64);
        if (t == 0) Ei[atom] = v + b3[0];
    }
    __syncthreads();

    // d2 = (W2 @ d3) * h2'(z2)
    if (t < H2) {
        float s = 0.0f;
        #pragma unroll 8
        for (int k = 0; k < H3; ++k) s += W2[t * H3 + k] * sd3[k];
        float h = sh2[t];
        sd2[t] = s * h * (1.0f - h);
    }
    __syncthreads();

    // d1 = (W1 @ d2) * h1'(z1)
    {
        float s = 0.0f;
        #pragma unroll 8
        for (int k = 0; k < H2; ++k) s += W1[t * H2 + k] * sd2[k];
        float h = sh1[t];
        sd1[t] = s * h * (1.0f - h);
    }
    __syncthreads();

    // dE/dx = W0 @ d1
    if (t < NFEAT) {
        float s = 0.0f;
        #pragma unroll 8
        for (int k = 0; k < H1; ++k) s += W0[t * H1 + k] * sd1[k];
        dE[atom * NFEAT + t] = s;
    }
}

// -------- Kernel 2: Etot[b] = sum_i Ei[b,i] --------
__global__ __launch_bounds__(256) void etot_kernel(const float* __restrict__ Ei,
                                                   float* __restrict__ Etot)
{
    const int b = blockIdx.x;
    const int t = threadIdx.x;
    float v = Ei[b * NA + t] + Ei[b * NA + t + 256];
    __shared__ float red[4];
    #pragma unroll
    for (int off = 32; off > 0; off >>= 1) v += __shfl_down(v, off, 64);
    if ((t & 63) == 0) red[t >> 6] = v;
    __syncthreads();
    if (t == 0) Etot[b] = red[0] + red[1] + red[2] + red[3];
}

// -------- Kernel 3: Force[b,i,d] = sum_m mask * dE[b, nb-1, f] * dfeat[b,i,m,f,d] --------
// one block (128 threads) per (b,i); thread t<126 owns (f,d) = (t/3, t%3)
__global__ __launch_bounds__(128) void force_kernel(
    const float* __restrict__ dfeat,     // [B,N,M,NFEAT,3]
    const int*   __restrict__ neighbor,  // [B,N,M]
    const float* __restrict__ dE,        // [B,N,NFEAT]
    float* __restrict__ Force)           // [B,N,3]
{
    const int bi = blockIdx.x;           // b*NA + i
    const int b  = bi / NA;
    const int t  = threadIdx.x;

    __shared__ int   s_nb[NM];
    __shared__ float s_dE[NM * NFEAT];
    __shared__ float s_acc[NFEAT * 3];

    if (t < NM) s_nb[t] = neighbor[bi * NM + t];
    __syncthreads();

    // gather masked dE rows for the 100 neighbors
    for (int i = t; i < NM * NFEAT; i += 128) {
        int m = i / NFEAT;
        int f = i - m * NFEAT;
        int n = s_nb[m];
        s_dE[i] = (n > 0) ? dE[(b * NA + (n - 1)) * NFEAT + f] : 0.0f;
    }
    __syncthreads();

    if (t < NFEAT * 3) {
        const int f = t / 3;
        const float* df = dfeat + (size_t)bi * NM * NFEAT * 3;
        float acc = 0.0f;
        #pragma unroll 4
        for (int m = 0; m < NM; ++m) {
            acc += s_dE[m * NFEAT + f] * df[m * (NFEAT * 3) + t];
        }
        s_acc[t] = acc;
    }
    __syncthreads();

    if (t < 3) {
        float s = 0.0f;
        #pragma unroll
        for (int f = 0; f < NFEAT; ++f) s += s_acc[f * 3 + t];
        Force[bi * 3 + t] = s;
    }
}

extern "C" void kernel_launch(void* const* d_in, const int* in_sizes, int n_in,
                              void* d_out, int out_size, void* d_ws, size_t ws_size,
                              hipStream_t stream) {
    const float* image    = (const float*)d_in[0];
    const float* dfeat    = (const float*)d_in[1];
    const int*   neighbor = (const int*)  d_in[2];
    const float* W0 = (const float*)d_in[3];
    const float* b0 = (const float*)d_in[4];
    const float* W1 = (const float*)d_in[5];
    const float* b1 = (const float*)d_in[6];
    const float* W2 = (const float*)d_in[7];
    const float* b2 = (const float*)d_in[8];
    const float* W3 = (const float*)d_in[9];
    const float* b3 = (const float*)d_in[10];

    float* out   = (float*)d_out;
    float* Etot  = out;                    // [8]
    float* Ei    = out + NB;               // [8*512]
    float* Force = out + NB + NB * NA;     // [8*512*3]
    float* dE    = (float*)d_ws;           // [8*512*42] scratch

    mlp_fwd_bwd<<<NB * NA, 256, 0, stream>>>(image, W0, b0, W1, b1, W2, b2, W3, b3, Ei, dE);
    etot_kernel<<<NB, 256, 0, stream>>>(Ei, Etot);
    force_kernel<<<NB * NA, 128, 0, stream>>>(dfeat, neighbor, dE, Force);
}

// Round 2
// 344.798 us; speedup vs baseline: 1.3225x; 1.3225x over previous
//
#include <hip/hip_runtime.h>

#define NFEAT 42
#define H1 256
#define H2 128
#define H3 64
#define NB 8
#define NA 512
#define NM 100
#define TA 8   // atoms per MLP block

__device__ __forceinline__ float sigmoidf(float z) {
    return 1.0f / (1.0f + __expf(-z));
}

// -------- Kernel 0: transpose weights into workspace (coalesced bwd reads) --------
__global__ __launch_bounds__(256) void transpose_weights(
    const float* __restrict__ W0, const float* __restrict__ W1, const float* __restrict__ W2,
    float* __restrict__ W0T, float* __restrict__ W1T, float* __restrict__ W2T)
{
    int i = blockIdx.x * 256 + threadIdx.x;
    if (i < NFEAT * H1) {           // W0 [42][256] -> W0T [256][42]
        int f = i / H1, k = i - f * H1;
        W0T[k * NFEAT + f] = W0[i];
    }
    if (i < H1 * H2) {              // W1 [256][128] -> W1T [128][256]
        int k = i / H2, j = i - k * H2;
        W1T[j * H1 + k] = W1[i];
    }
    if (i < H2 * H3) {              // W2 [128][64] -> W2T [64][128]
        int j = i / H3, k = i - j * H3;
        W2T[k * H2 + j] = W2[i];
    }
}

// -------- Kernel 1: per-8-atom MLP forward + backward (dE/dx) --------
__global__ __launch_bounds__(256) void mlp_fwd_bwd(
    const float* __restrict__ image,
    const float* __restrict__ W0, const float* __restrict__ b0,
    const float* __restrict__ W1, const float* __restrict__ b1,
    const float* __restrict__ W2, const float* __restrict__ b2,
    const float* __restrict__ W3, const float* __restrict__ b3,
    const float* __restrict__ W0T, const float* __restrict__ W1T, const float* __restrict__ W2T,
    float* __restrict__ Ei,   // [B*N]
    float* __restrict__ dE)   // [B*N, NFEAT]
{
    const int t = threadIdx.x;
    const int atom0 = blockIdx.x * TA;

    __shared__ float sx[TA][NFEAT];
    __shared__ __align__(16) float sh1[TA][H1];
    __shared__ __align__(16) float sh2[TA][H2];
    __shared__ __align__(16) float sh3[TA][H3];
    __shared__ __align__(16) float sd3[TA][H3];
    __shared__ __align__(16) float sd2[TA][H2];
    __shared__ __align__(16) float sd1[TA][H1];

    // stage inputs
    for (int i = t; i < TA * NFEAT; i += 256) {
        int a = i / NFEAT, f = i - a * NFEAT;
        sx[a][f] = image[(atom0 + a) * NFEAT + f];
    }
    __syncthreads();

    // ---- layer 0: 42 -> 256, sigmoid (thread = out neuron, 8 atoms) ----
    {
        float acc[TA];
        #pragma unroll
        for (int a = 0; a < TA; ++a) acc[a] = 0.f;
        for (int k = 0; k < NFEAT; ++k) {
            float w = W0[k * H1 + t];
            #pragma unroll
            for (int a = 0; a < TA; ++a) acc[a] += sx[a][k] * w;
        }
        float bb = b0[t];
        #pragma unroll
        for (int a = 0; a < TA; ++a) sh1[a][t] = sigmoidf(acc[a] + bb);
    }
    __syncthreads();

    // ---- layer 1: 256 -> 128, sigmoid (j = t&127, 4 atoms per thread) ----
    {
        const int j = t & 127, g = t >> 7, a0 = g * 4;
        float acc[4] = {0.f, 0.f, 0.f, 0.f};
        for (int kk = 0; kk < H1 / 4; ++kk) {
            float w0_ = W1[(4 * kk + 0) * H2 + j];
            float w1_ = W1[(4 * kk + 1) * H2 + j];
            float w2_ = W1[(4 * kk + 2) * H2 + j];
            float w3_ = W1[(4 * kk + 3) * H2 + j];
            #pragma unroll
            for (int a = 0; a < 4; ++a) {
                float4 h = ((const float4*)sh1[a0 + a])[kk];
                acc[a] += h.x * w0_ + h.y * w1_ + h.z * w2_ + h.w * w3_;
            }
        }
        float bb = b1[j];
        #pragma unroll
        for (int a = 0; a < 4; ++a) sh2[a0 + a][j] = sigmoidf(acc[a] + bb);
    }
    __syncthreads();

    // ---- layer 2: 128 -> 64, sigmoid (j = t&63, 2 atoms per thread) ----
    {
        const int j = t & 63, g = t >> 6, a0 = g * 2;
        float acc[2] = {0.f, 0.f};
        for (int kk = 0; kk < H2 / 4; ++kk) {
            float w0_ = W2[(4 * kk + 0) * H3 + j];
            float w1_ = W2[(4 * kk + 1) * H3 + j];
            float w2_ = W2[(4 * kk + 2) * H3 + j];
            float w3_ = W2[(4 * kk + 3) * H3 + j];
            #pragma unroll
            for (int a = 0; a < 2; ++a) {
                float4 h = ((const float4*)sh2[a0 + a])[kk];
                acc[a] += h.x * w0_ + h.y * w1_ + h.z * w2_ + h.w * w3_;
            }
        }
        float bb = b2[j];
        #pragma unroll
        for (int a = 0; a < 2; ++a) sh3[a0 + a][j] = sigmoidf(acc[a] + bb);
    }
    __syncthreads();

    // ---- output layer 64 -> 1 (linear) + sd3; each wave handles 2 atoms ----
    {
        const int lane = t & 63, wv = t >> 6, a0 = wv * 2;
        float w = W3[lane];
        float bb = b3[0];
        #pragma unroll
        for (int a = a0; a < a0 + 2; ++a) {
            float h = sh3[a][lane];
            sd3[a][lane] = w * h * (1.f - h);
            float v = w * h;
            #pragma unroll
            for (int off = 32; off > 0; off >>= 1) v += __shfl_down(v, off, 64);
            if (lane == 0) Ei[atom0 + a] = v + bb;
        }
    }
    __syncthreads();

    // ---- bwd: d2 = (W2 @ d3) * h2' (j = t&127, 4 atoms) ----
    {
        const int j = t & 127, g = t >> 7, a0 = g * 4;
        float acc[4] = {0.f, 0.f, 0.f, 0.f};
        for (int kk = 0; kk < H3 / 4; ++kk) {
            float w0_ = W2T[(4 * kk + 0) * H2 + j];
            float w1_ = W2T[(4 * kk + 1) * H2 + j];
            float w2_ = W2T[(4 * kk + 2) * H2 + j];
            float w3_ = W2T[(4 * kk + 3) * H2 + j];
            #pragma unroll
            for (int a = 0; a < 4; ++a) {
                float4 d = ((const float4*)sd3[a0 + a])[kk];
                acc[a] += d.x * w0_ + d.y * w1_ + d.z * w2_ + d.w * w3_;
            }
        }
        #pragma unroll
        for (int a = 0; a < 4; ++a) {
            float h = sh2[a0 + a][j];
            sd2[a0 + a][j] = acc[a] * h * (1.f - h);
        }
    }
    __syncthreads();

    // ---- bwd: d1 = (W1 @ d2) * h1' (k = t, all 8 atoms) ----
    {
        float acc[TA];
        #pragma unroll
        for (int a = 0; a < TA; ++a) acc[a] = 0.f;
        for (int jj = 0; jj < H2 / 4; ++jj) {
            float w0_ = W1T[(4 * jj + 0) * H1 + t];
            float w1_ = W1T[(4 * jj + 1) * H1 + t];
            float w2_ = W1T[(4 * jj + 2) * H1 + t];
            float w3_ = W1T[(4 * jj + 3) * H1 + t];
            #pragma unroll
            for (int a = 0; a < TA; ++a) {
                float4 d = ((const float4*)sd2[a])[jj];
                acc[a] += d.x * w0_ + d.y * w1_ + d.z * w2_ + d.w * w3_;
            }
        }
        #pragma unroll
        for (int a = 0; a < TA; ++a) {
            float h = sh1[a][t];
            sd1[a][t] = acc[a] * h * (1.f - h);
        }
    }
    __syncthreads();

    // ---- bwd: dE/dx = W0 @ d1 (f = t&63 < 42, 2 atoms) ----
    {
        const int f = t & 63, g = t >> 6, a0 = g * 2;
        if (f < NFEAT) {
            float acc[2] = {0.f, 0.f};
            for (int kk = 0; kk < H1 / 4; ++kk) {
                float w0_ = W0T[(4 * kk + 0) * NFEAT + f];
                float w1_ = W0T[(4 * kk + 1) * NFEAT + f];
                float w2_ = W0T[(4 * kk + 2) * NFEAT + f];
                float w3_ = W0T[(4 * kk + 3) * NFEAT + f];
                #pragma unroll
                for (int a = 0; a < 2; ++a) {
                    float4 d = ((const float4*)sd1[a0 + a])[kk];
                    acc[a] += d.x * w0_ + d.y * w1_ + d.z * w2_ + d.w * w3_;
                }
            }
            #pragma unroll
            for (int a = 0; a < 2; ++a)
                dE[(atom0 + a0 + a) * NFEAT + f] = acc[a];
        }
    }
}

// -------- Kernel 2: Etot[b] = sum_i Ei[b,i] --------
__global__ __launch_bounds__(256) void etot_kernel(const float* __restrict__ Ei,
                                                   float* __restrict__ Etot)
{
    const int b = blockIdx.x;
    const int t = threadIdx.x;
    float v = Ei[b * NA + t] + Ei[b * NA + t + 256];
    __shared__ float red[4];
    #pragma unroll
    for (int off = 32; off > 0; off >>= 1) v += __shfl_down(v, off, 64);
    if ((t & 63) == 0) red[t >> 6] = v;
    __syncthreads();
    if (t == 0) Etot[b] = red[0] + red[1] + red[2] + red[3];
}

// -------- Kernel 3: Force via float4-coalesced dfeat stream --------
// one block (256 threads) per (b,i); 8 neighbor rows (1008 B) per iteration
__global__ __launch_bounds__(256) void force_kernel(
    const float* __restrict__ dfeat,     // [B,N,M,NFEAT,3] = [bi][100][126]
    const int*   __restrict__ neighbor,  // [B,N,M]
    const float* __restrict__ dE,        // [B,N,NFEAT]
    float* __restrict__ Force)           // [B,N,3]
{
    const int bi = blockIdx.x;
    const int b  = bi >> 9;
    const int t  = threadIdx.x;

    __shared__ int   s_nb[NM];
    __shared__ float s_dE[104 * NFEAT];   // rows 100..103 zero-padded
    __shared__ float s_part[1008];
    __shared__ float s_red[126];

    if (t < NM) s_nb[t] = neighbor[bi * NM + t];
    for (int i = t; i < 4 * NFEAT; i += 256) s_dE[NM * NFEAT + i] = 0.f;
    __syncthreads();

    for (int i = t; i < NM * NFEAT; i += 256) {
        int m = i / NFEAT, f = i - m * NFEAT;
        int n = s_nb[m];
        s_dE[i] = (n > 0) ? dE[((b << 9) + n - 1) * NFEAT + f] : 0.f;
    }
    __syncthreads();

    if (t < 252) {
        const int e4 = 4 * t;
        int off[4];
        #pragma unroll
        for (int c = 0; c < 4; ++c) {
            int ee = e4 + c;
            int r  = ee / 126;            // row within 8-row group
            int e  = ee - r * 126;        // element within row (f*3+d)
            off[c] = r * NFEAT + e / 3;   // s_dE offset relative to m0*NFEAT
        }
        const float* base = dfeat + (size_t)bi * (NM * NFEAT * 3);
        float acc[4] = {0.f, 0.f, 0.f, 0.f};

        for (int m0 = 0; m0 < 96; m0 += 8) {
            float4 v = *(const float4*)(base + m0 * 126 + e4);
            const float* sd = s_dE + m0 * NFEAT;
            acc[0] += v.x * sd[off[0]];
            acc[1] += v.y * sd[off[1]];
            acc[2] += v.z * sd[off[2]];
            acc[3] += v.w * sd[off[3]];
        }
        {   // tail: rows 96..103; rows >=100 hit zero-padded s_dE.
            // For all but the global last block the float4 read of rows 100..103
            // lands in the next block's dfeat (in-bounds, finite); for the last
            // block do guarded scalar loads.
            const int m0 = 96;
            float vv[4];
            if (bi != NB * NA - 1) {
                float4 v = *(const float4*)(base + m0 * 126 + e4);
                vv[0] = v.x; vv[1] = v.y; vv[2] = v.z; vv[3] = v.w;
            } else {
                #pragma unroll
                for (int c = 0; c < 4; ++c) {
                    int r = (e4 + c) / 126;
                    vv[c] = (m0 + r < NM) ? base[m0 * 126 + e4 + c] : 0.f;
                }
            }
            const float* sd = s_dE + m0 * NFEAT;
            #pragma unroll
            for (int c = 0; c < 4; ++c) acc[c] += vv[c] * sd[off[c]];
        }
        #pragma unroll
        for (int c = 0; c < 4; ++c) s_part[e4 + c] = acc[c];
    }
    __syncthreads();

    if (t < 126) {
        float s = 0.f;
        #pragma unroll
        for (int r = 0; r < 8; ++r) s += s_part[r * 126 + t];
        s_red[t] = s;
    }
    __syncthreads();

    if (t < 3) {
        float s = 0.f;
        #pragma unroll
        for (int f = 0; f < NFEAT; ++f) s += s_red[f * 3 + t];
        Force[bi * 3 + t] = s;
    }
}

extern "C" void kernel_launch(void* const* d_in, const int* in_sizes, int n_in,
                              void* d_out, int out_size, void* d_ws, size_t ws_size,
                              hipStream_t stream) {
    const float* image    = (const float*)d_in[0];
    const float* dfeat    = (const float*)d_in[1];
    const int*   neighbor = (const int*)  d_in[2];
    const float* W0 = (const float*)d_in[3];
    const float* b0 = (const float*)d_in[4];
    const float* W1 = (const float*)d_in[5];
    const float* b1 = (const float*)d_in[6];
    const float* W2 = (const float*)d_in[7];
    const float* b2 = (const float*)d_in[8];
    const float* W3 = (const float*)d_in[9];
    const float* b3 = (const float*)d_in[10];

    float* out   = (float*)d_out;
    float* Etot  = out;                    // [8]
    float* Ei    = out + NB;               // [8*512]
    float* Force = out + NB + NB * NA;     // [8*512*3]

    float* dE  = (float*)d_ws;             // [4096*42]
    float* W0T = dE  + NB * NA * NFEAT;    // [256*42]
    float* W1T = W0T + NFEAT * H1;         // [128*256]
    float* W2T = W1T + H1 * H2;            // [64*128]

    transpose_weights<<<(H1 * H2 + 255) / 256, 256, 0, stream>>>(W0, W1, W2, W0T, W1T, W2T);
    mlp_fwd_bwd<<<(NB * NA) / TA, 256, 0, stream>>>(image, W0, b0, W1, b1, W2, b2, W3, b3,
                                                    W0T, W1T, W2T, Ei, dE);
    etot_kernel<<<NB, 256, 0, stream>>>(Ei, Etot);
    force_kernel<<<NB * NA, 256, 0, stream>>>(dfeat, neighbor, dE, Force);
}